// Round 1
// baseline (156.712 us; speedup 1.0000x reference)
//
#include <hip/hip_runtime.h>
#include <math.h>

// Problem constants (fixed by the reference file)
#define H_DIM 1024
#define N2    32        // N/2 modes
#define L_LEN 8192
#define TPB   256
#define LPT   4         // l-values per thread; block covers TPB*LPT = 1024 l's

// out[h,l] = 2 * Re( sum_n Ceff[h,n] * exp(dtA[h,n] * l) )
// Ceff = Cc * (exp(dtA)-1)/A,  dtA = A*dt,  A = -exp(log_A_real) + i*A_imag
__global__ __launch_bounds__(TPB) void s4d_vandermonde_kernel(
    const float* __restrict__ C,           // (H, N2, 2)
    const float* __restrict__ log_dt,      // (H,)
    const float* __restrict__ log_A_real,  // (H, N2)
    const float* __restrict__ A_imag,      // (H, N2)
    float* __restrict__ out)               // (H, L)
{
    // per-mode params: x = 2*Re(Ceff), y = -2*Im(Ceff), z = re(dtA), w = im(dtA)/(2*pi)
    __shared__ float4 prm[N2];

    const int h   = blockIdx.y;
    const int tid = threadIdx.x;

    if (tid < N2) {
        const int n   = tid;
        const int idx = h * N2 + n;
        float dt  = expf(log_dt[h]);
        float are = -expf(log_A_real[idx]);   // Re(A)
        float aim = A_imag[idx];              // Im(A)
        float xr  = are * dt;                 // Re(dtA)
        float xi  = aim * dt;                 // Im(dtA)
        // exp(dtA) - 1  (accurate libm for the small per-block setup)
        float ex = expf(xr);
        float s  = sinf(xi);
        float c  = cosf(xi);
        float er = ex * c - 1.0f;
        float ei = ex * s;
        // Cc * (er + i*ei)
        float cr = C[idx * 2 + 0];
        float ci = C[idx * 2 + 1];
        float nr = cr * er - ci * ei;
        float ni = cr * ei + ci * er;
        // divide by A: num * conj(A) / |A|^2
        float inv_den = 1.0f / (are * are + aim * aim);
        float Cr = (nr * are + ni * aim) * inv_den;
        float Ci = (ni * are - nr * aim) * inv_den;
        prm[n] = make_float4(2.0f * Cr,
                             -2.0f * Ci,
                             xr,                            // natural-log decay rate
                             xi * 0.15915494309189535f);    // phase in revolutions/step
    }
    __syncthreads();

    const int l0 = blockIdx.x * (TPB * LPT) + tid;
    float lf[LPT];
    float acc[LPT];
#pragma unroll
    for (int k = 0; k < LPT; ++k) {
        lf[k]  = (float)(l0 + k * TPB);
        acc[k] = 0.0f;
    }

#pragma unroll 8
    for (int n = 0; n < N2; ++n) {
        float4 p = prm[n];
#pragma unroll
        for (int k = 0; k < LPT; ++k) {
            float rv = p.w * lf[k];            // phase in revolutions
            rv = rv - floorf(rv);              // reduce to [0,1) -> v_fract
            float s = __builtin_amdgcn_sinf(rv);  // sin(2*pi*rv)
            float c = __builtin_amdgcn_cosf(rv);  // cos(2*pi*rv)
            float e = __expf(p.z * lf[k]);        // decay amplitude
            // += e * (2Cr*cos - 2Ci*sin)
            acc[k] = fmaf(e, fmaf(p.y, s, p.x * c), acc[k]);
        }
    }

    float* orow = out + (size_t)h * L_LEN + (size_t)blockIdx.x * (TPB * LPT);
#pragma unroll
    for (int k = 0; k < LPT; ++k) {
        orow[tid + k * TPB] = acc[k];
    }
}

extern "C" void kernel_launch(void* const* d_in, const int* in_sizes, int n_in,
                              void* d_out, int out_size, void* d_ws, size_t ws_size,
                              hipStream_t stream) {
    const float* C          = (const float*)d_in[0];
    const float* log_dt     = (const float*)d_in[1];
    const float* log_A_real = (const float*)d_in[2];
    const float* A_imag     = (const float*)d_in[3];
    float* out              = (float*)d_out;

    dim3 grid(L_LEN / (TPB * LPT), H_DIM);  // (8, 1024)
    dim3 block(TPB);
    hipLaunchKernelGGL(s4d_vandermonde_kernel, grid, block, 0, stream,
                       C, log_dt, log_A_real, A_imag, out);
}

// Round 2
// 106.184 us; speedup vs baseline: 1.4758x; 1.4758x over previous
//
#include <hip/hip_runtime.h>
#include <math.h>

// Problem constants (fixed by the reference file)
#define H_DIM  1024
#define N2     32        // N/2 modes
#define L_LEN  8192
#define TPB    256
#define NSTEPS 16        // l-values per thread (stride TPB); block covers TPB*NSTEPS = 4096
#define GRIDX  (L_LEN / (TPB * NSTEPS))   // = 2

// out[h,l] = Re( sum_n 2*Ceff[h,n] * z_n^l ),  z_n = exp(dtA_n)
// Recurrence: u_{l+TPB} = u_l * w,  w = z^TPB  (wave-uniform per mode)
__global__ __launch_bounds__(TPB) void s4d_recurrence_kernel(
    const float* __restrict__ C,           // (H, N2, 2)
    const float* __restrict__ log_dt,      // (H,)
    const float* __restrict__ log_A_real,  // (H, N2)
    const float* __restrict__ A_imag,      // (H, N2)
    float* __restrict__ out)               // (H, L)
{
    // prmA: (2*Re(Ceff), 2*Im(Ceff), Re(w), Im(w))
    // prmB: (Re(dtA), Im(dtA)/(2*pi))  for chain init
    __shared__ float4 prmA[N2];
    __shared__ float2 prmB[N2];

    const int h   = blockIdx.y;
    const int tid = threadIdx.x;

    if (tid < N2) {
        const int n   = tid;
        const int idx = h * N2 + n;
        float dt  = expf(log_dt[h]);
        float are = -expf(log_A_real[idx]);   // Re(A)
        float aim = A_imag[idx];              // Im(A)
        float xr  = are * dt;                 // Re(dtA)
        float xi  = aim * dt;                 // Im(dtA)
        // Ceff = Cc * (exp(dtA)-1)/A   (fp32 libm; once per block)
        float ex = expf(xr);
        float s  = sinf(xi);
        float c  = cosf(xi);
        float er = ex * c - 1.0f;
        float ei = ex * s;
        float cr = C[idx * 2 + 0];
        float ci = C[idx * 2 + 1];
        float nr = cr * er - ci * ei;
        float ni = cr * ei + ci * er;
        float inv_den = 1.0f / (are * are + aim * aim);
        float Cr = (nr * are + ni * aim) * inv_den;
        float Ci = (ni * are - nr * aim) * inv_den;
        // w = z^TPB = exp(dtA * TPB) in double precision (phase up to ~2500 rad)
        double pxr = (double)xr * (double)TPB;
        double pxi = (double)xi * (double)TPB;
        double rho = exp(pxr);
        float wr = (float)(rho * cos(pxi));
        float wi = (float)(rho * sin(pxi));
        prmA[n] = make_float4(2.0f * Cr, 2.0f * Ci, wr, wi);
        prmB[n] = make_float2(xr, xi * 0.15915494309189535f);
    }
    __syncthreads();

    const int l_base = blockIdx.x * (TPB * NSTEPS);
    const float lf   = (float)(l_base + tid);

    float acc[NSTEPS];
#pragma unroll
    for (int s = 0; s < NSTEPS; ++s) acc[s] = 0.0f;

    for (int n = 0; n < N2; ++n) {
        const float4 pA = prmA[n];
        const float2 pB = prmB[n];

        // init: u = 2*Ceff * z^(l_base+tid)
        float e  = __expf(pB.x * lf);
        float rv = pB.y * lf;
        rv = rv - floorf(rv);
        float sn = __builtin_amdgcn_sinf(rv);   // sin(2*pi*rv)
        float cs = __builtin_amdgcn_cosf(rv);   // cos(2*pi*rv)
        float zr = e * cs;
        float zi = e * sn;
        float ur = pA.x * zr - pA.y * zi;
        float ui = pA.x * zi + pA.y * zr;

        const float wr = pA.z;
        const float wi = pA.w;
#pragma unroll
        for (int s = 0; s < NSTEPS; ++s) {
            acc[s] += ur;
            float nr = fmaf(-ui, wi, ur * wr);  // ur*wr - ui*wi
            float ni = fmaf( ui, wr, ur * wi);  // ur*wi + ui*wr
            ur = nr;
            ui = ni;
        }
    }

    float* orow = out + (size_t)h * L_LEN + l_base;
#pragma unroll
    for (int s = 0; s < NSTEPS; ++s) {
        orow[s * TPB + tid] = acc[s];
    }
}

extern "C" void kernel_launch(void* const* d_in, const int* in_sizes, int n_in,
                              void* d_out, int out_size, void* d_ws, size_t ws_size,
                              hipStream_t stream) {
    const float* C          = (const float*)d_in[0];
    const float* log_dt     = (const float*)d_in[1];
    const float* log_A_real = (const float*)d_in[2];
    const float* A_imag     = (const float*)d_in[3];
    float* out              = (float*)d_out;

    dim3 grid(GRIDX, H_DIM);   // (2, 1024)
    dim3 block(TPB);
    hipLaunchKernelGGL(s4d_recurrence_kernel, grid, block, 0, stream,
                       C, log_dt, log_A_real, A_imag, out);
}

// Round 3
// 94.693 us; speedup vs baseline: 1.6549x; 1.1213x over previous
//
#include <hip/hip_runtime.h>
#include <math.h>

// Problem constants (fixed by the reference file)
#define H_DIM  1024
#define N2     32        // N/2 modes
#define L_LEN  8192
#define TPB    256
#define NSTEPS 32        // l-values per thread (stride TPB); one block covers all of L

// out[h,l] = Re( sum_n 2*Ceff[h,n] * z_n^l ),  z_n = exp(dtA_n)
// Per-thread chain over s: l = tid + s*TPB.
// y_s = 2*Re(U * w^s), U = 2*Ceff*z^tid, w = z^TPB  satisfies the REAL recurrence
//   y_{s+1} = p*y_s - q*y_{s-1},  p = 2*Re(w), q = |w|^2   (roots w, conj(w))
__global__ __launch_bounds__(TPB) void s4d_real_recurrence_kernel(
    const float* __restrict__ C,           // (H, N2, 2)
    const float* __restrict__ log_dt,      // (H,)
    const float* __restrict__ log_A_real,  // (H, N2)
    const float* __restrict__ A_imag,      // (H, N2)
    float* __restrict__ out)               // (H, L)
{
    // prmA: (2*Re(Ceff), 2*Im(Ceff), Re(dtA), Im(dtA)/(2*pi))
    // prmB: (Re(w), Im(w), p, q)
    __shared__ float4 prmA[N2];
    __shared__ float4 prmB[N2];

    const int h   = blockIdx.x;
    const int tid = threadIdx.x;

    if (tid < N2) {
        const int n   = tid;
        const int idx = h * N2 + n;
        float dt  = expf(log_dt[h]);
        float are = -expf(log_A_real[idx]);   // Re(A)
        float aim = A_imag[idx];              // Im(A)
        float xr  = are * dt;                 // Re(dtA)
        float xi  = aim * dt;                 // Im(dtA)
        // Ceff = Cc * (exp(dtA)-1)/A   (fp32 libm; once per block)
        float ex = expf(xr);
        float s  = sinf(xi);
        float c  = cosf(xi);
        float er = ex * c - 1.0f;
        float ei = ex * s;
        float cr = C[idx * 2 + 0];
        float ci = C[idx * 2 + 1];
        float nr = cr * er - ci * ei;
        float ni = cr * ei + ci * er;
        float inv_den = 1.0f / (are * are + aim * aim);
        float Cr = (nr * are + ni * aim) * inv_den;
        float Ci = (ni * are - nr * aim) * inv_den;
        // w = z^TPB = exp(dtA * TPB) in double precision (phase up to ~2500 rad)
        double pxr = (double)xr * (double)TPB;
        double pxi = (double)xi * (double)TPB;
        double rho = exp(pxr);
        float wr = (float)(rho * cos(pxi));
        float wi = (float)(rho * sin(pxi));
        float p  = 2.0f * wr;
        float q  = (float)(rho * rho);
        prmA[n] = make_float4(2.0f * Cr, 2.0f * Ci,
                              xr, xi * 0.15915494309189535f);
        prmB[n] = make_float4(wr, wi, p, q);
    }
    __syncthreads();

    const float lf = (float)tid;   // l = tid + s*TPB; phase arg stays tiny (<400 rev)

    float acc[NSTEPS];
#pragma unroll
    for (int s = 0; s < NSTEPS; ++s) acc[s] = 0.0f;

    // process modes in pairs for ILP (two independent recurrence chains)
    for (int n = 0; n < N2; n += 2) {
        const float4 a0 = prmA[n];
        const float4 b0 = prmB[n];
        const float4 a1 = prmA[n + 1];
        const float4 b1 = prmB[n + 1];

        // --- init chain 0: U0 = 2*Ceff0 * z0^tid ---
        float e0  = __expf(a0.z * lf);
        float rv0 = a0.w * lf;  rv0 -= floorf(rv0);
        float sn0 = __builtin_amdgcn_sinf(rv0);
        float cs0 = __builtin_amdgcn_cosf(rv0);
        float zr0 = e0 * cs0, zi0 = e0 * sn0;
        float ur0 = fmaf(a0.x, zr0, -(a0.y * zi0));
        float ui0 = fmaf(a0.x, zi0,  (a0.y * zr0));
        float yp0 = ur0;                                   // y_0
        float yc0 = fmaf(ur0, b0.x, -(ui0 * b0.y));        // y_1 = Re(U0*w0)

        // --- init chain 1 ---
        float e1  = __expf(a1.z * lf);
        float rv1 = a1.w * lf;  rv1 -= floorf(rv1);
        float sn1 = __builtin_amdgcn_sinf(rv1);
        float cs1 = __builtin_amdgcn_cosf(rv1);
        float zr1 = e1 * cs1, zi1 = e1 * sn1;
        float ur1 = fmaf(a1.x, zr1, -(a1.y * zi1));
        float ui1 = fmaf(a1.x, zi1,  (a1.y * zr1));
        float yp1 = ur1;
        float yc1 = fmaf(ur1, b1.x, -(ui1 * b1.y));

        const float p0 = b0.z, q0 = b0.w;
        const float p1 = b1.z, q1 = b1.w;

        acc[0] += yp0 + yp1;
#pragma unroll
        for (int s = 1; s < NSTEPS; ++s) {
            acc[s] += yc0 + yc1;
            float t0 = q0 * yp0;                // independent pair: SLP/pk candidate
            float t1 = q1 * yp1;
            float n0 = fmaf(p0, yc0, -t0);
            float n1 = fmaf(p1, yc1, -t1);
            yp0 = yc0;  yc0 = n0;
            yp1 = yc1;  yc1 = n1;
        }
    }

    float* orow = out + (size_t)h * L_LEN;
#pragma unroll
    for (int s = 0; s < NSTEPS; ++s) {
        orow[s * TPB + tid] = acc[s];
    }
}

extern "C" void kernel_launch(void* const* d_in, const int* in_sizes, int n_in,
                              void* d_out, int out_size, void* d_ws, size_t ws_size,
                              hipStream_t stream) {
    const float* C          = (const float*)d_in[0];
    const float* log_dt     = (const float*)d_in[1];
    const float* log_A_real = (const float*)d_in[2];
    const float* A_imag     = (const float*)d_in[3];
    float* out              = (float*)d_out;

    dim3 grid(H_DIM);   // one block per h
    dim3 block(TPB);
    hipLaunchKernelGGL(s4d_real_recurrence_kernel, grid, block, 0, stream,
                       C, log_dt, log_A_real, A_imag, out);
}